// Round 1
// baseline (6336.330 us; speedup 1.0000x reference)
//
#include <hip/hip_runtime.h>
#include <hip/hip_bf16.h>
#include <hip/hip_fp16.h>

typedef _Float16 f16;
typedef __hip_bfloat16 bf16;
typedef short bf16x8 __attribute__((ext_vector_type(8)));
typedef float f32x4 __attribute__((ext_vector_type(4)));
typedef _Float16 f16x2 __attribute__((ext_vector_type(2)));

#define HDIM 256
#define G4   1024
#define TT   2048
#define NB   64
#define NTOK (64*2048)
#define MPAD 384   // 341 padded to 384 (6 x 64)

// ---------------- helpers ----------------
__device__ __forceinline__ float dot2f(unsigned a, unsigned b, float c) {
#if __has_builtin(__builtin_amdgcn_fdot2)
    return __builtin_amdgcn_fdot2(__builtin_bit_cast(f16x2, a),
                                  __builtin_bit_cast(f16x2, b), c, false);
#else
    f16x2 x = __builtin_bit_cast(f16x2, a), y = __builtin_bit_cast(f16x2, b);
    return c + (float)x[0]*(float)y[0] + (float)x[1]*(float)y[1];
#endif
}

__device__ __forceinline__ float gelu_tanh(float x) {
    // jax.nn.gelu default (approximate=True)
    float x3 = x*x*x;
    float t = tanhf(0.7978845608028654f * (x + 0.044715f * x3));
    return 0.5f * x * (1.0f + t);
}

// ---------------- prep: dtype conversion + padding ----------------
__global__ void k_prep_wr(const float* __restrict__ W, const float* __restrict__ R,
                          bf16* __restrict__ Wb, f16* __restrict__ Rf) {
    int i = blockIdx.x*256 + threadIdx.x;          // 262144 total
    Wb[i] = __float2bfloat16(W[i]);
    Rf[i] = (f16)R[i];
}

__global__ void k_prep_gu(const float* __restrict__ gW, const float* __restrict__ uW,
                          const float* __restrict__ gb, const float* __restrict__ ub,
                          bf16* __restrict__ gWb, bf16* __restrict__ uWb,
                          float* __restrict__ gbp, float* __restrict__ ubp) {
    int i = blockIdx.x*256 + threadIdx.x;          // 384*256 total
    int r = i >> 8, c = i & 255;
    gWb[i] = __float2bfloat16(r < 341 ? gW[r*256 + c] : 0.f);
    uWb[i] = __float2bfloat16(r < 341 ? uW[r*256 + c] : 0.f);
    if (i < 384) {
        gbp[i] = i < 341 ? gb[i] : 0.f;
        ubp[i] = i < 341 ? ub[i] : 0.f;
    }
}

__global__ void k_prep_down(const float* __restrict__ dW, bf16* __restrict__ dWb) {
    int i = blockIdx.x*256 + threadIdx.x;          // 256*384 total
    int r = i / 384, c = i % 384;
    dWb[i] = __float2bfloat16(c < 341 ? dW[r*341 + c] : 0.f);
}

// ---------------- LayerNorm 1: f32 -> bf16 ----------------
__global__ __launch_bounds__(256) void k_ln1(const float* __restrict__ x,
        const float* __restrict__ w, const float* __restrict__ b,
        bf16* __restrict__ nx) {
    int wave = threadIdx.x >> 6, lane = threadIdx.x & 63;
    long tok = (long)blockIdx.x * 4 + wave;
    float4 v = ((const float4*)(x + tok*HDIM))[lane];
    float s = v.x + v.y + v.z + v.w;
    float q = v.x*v.x + v.y*v.y + v.z*v.z + v.w*v.w;
    #pragma unroll
    for (int m = 1; m < 64; m <<= 1) { s += __shfl_xor(s, m, 64); q += __shfl_xor(q, m, 64); }
    float mean = s * (1.0f/HDIM);
    float rs = rsqrtf(q*(1.0f/HDIM) - mean*mean + 1e-5f);
    float4 wv = ((const float4*)w)[lane];
    float4 bv = ((const float4*)b)[lane];
    bf16 tmp[4];
    tmp[0] = __float2bfloat16((v.x-mean)*rs*wv.x + bv.x);
    tmp[1] = __float2bfloat16((v.y-mean)*rs*wv.y + bv.y);
    tmp[2] = __float2bfloat16((v.z-mean)*rs*wv.z + bv.z);
    tmp[3] = __float2bfloat16((v.w-mean)*rs*wv.w + bv.w);
    *(ushort4*)(nx + tok*HDIM + lane*4) = *(ushort4*)tmp;
}

// ---------------- LayerNorm 2 + residual: f16 mlp + f32 x -> f32 out ----------------
__global__ __launch_bounds__(256) void k_ln2(const f16* __restrict__ mlp,
        const float* __restrict__ x, const float* __restrict__ w,
        const float* __restrict__ b, float* __restrict__ out) {
    int wave = threadIdx.x >> 6, lane = threadIdx.x & 63;
    long tok = (long)blockIdx.x * 4 + wave;
    const f16* mr = mlp + tok*HDIM + lane*4;
    float4 v; v.x = (float)mr[0]; v.y = (float)mr[1]; v.z = (float)mr[2]; v.w = (float)mr[3];
    float s = v.x + v.y + v.z + v.w;
    float q = v.x*v.x + v.y*v.y + v.z*v.z + v.w*v.w;
    #pragma unroll
    for (int m = 1; m < 64; m <<= 1) { s += __shfl_xor(s, m, 64); q += __shfl_xor(q, m, 64); }
    float mean = s * (1.0f/HDIM);
    float rs = rsqrtf(q*(1.0f/HDIM) - mean*mean + 1e-5f);
    float4 wv = ((const float4*)w)[lane];
    float4 bv = ((const float4*)b)[lane];
    float4 xv = ((const float4*)(x + tok*HDIM))[lane];
    float4 ov;
    ov.x = (v.x-mean)*rs*wv.x + bv.x + xv.x;
    ov.y = (v.y-mean)*rs*wv.y + bv.y + xv.y;
    ov.z = (v.z-mean)*rs*wv.z + bv.z + xv.z;
    ov.w = (v.w-mean)*rs*wv.w + bv.w + xv.w;
    ((float4*)(out + tok*HDIM))[lane] = ov;
}

// ---------------- GEMM: C[M x N] = A[M x K] * B[N x K]^T + bias ----------------
enum { MODE_F16 = 0, MODE_GELU_F16 = 1, MODE_MUL_BF16 = 2 };

template<int MODE>
__global__ __launch_bounds__(256) void k_gemm(
    const bf16* __restrict__ A, const bf16* __restrict__ Bm,
    const float* __restrict__ bias, void* __restrict__ Cv,
    const f16* __restrict__ gatebuf,
    int K, int lda, int ldb, int ldc, int ldg)
{
    // BM=128, BN=64, BK=64; rows stored as 64 bf16 = 128B = 8x16B slots, XOR-swizzled
    __shared__ char Al[128*128];
    __shared__ char Bl[64*128];
    const int tid = threadIdx.x;
    const long bm = (long)blockIdx.x * 128;
    const int bn = blockIdx.y * 64;
    const int wave = tid >> 6, lane = tid & 63;
    const int wm = wave >> 1, wn = wave & 1;        // 2x2 waves, each 64x32
    const int l16 = lane & 15, lq = lane >> 4;
    f32x4 acc[4][2] = {};
    for (int k0 = 0; k0 < K; k0 += 64) {
        #pragma unroll
        for (int p = 0; p < 4; ++p) {               // A: 128 rows x 8 chunks
            int ci = tid + p*256;
            int row = ci >> 3, s = ci & 7;
            uint4 d = *(const uint4*)(A + (bm + row)*lda + k0 + s*8);
            *(uint4*)(Al + row*128 + ((s ^ (row&7))<<4)) = d;
        }
        #pragma unroll
        for (int p = 0; p < 2; ++p) {               // B: 64 rows x 8 chunks
            int ci = tid + p*256;
            int row = ci >> 3, s = ci & 7;
            uint4 d = *(const uint4*)(Bm + (long)(bn + row)*ldb + k0 + s*8);
            *(uint4*)(Bl + row*128 + ((s ^ (row&7))<<4)) = d;
        }
        __syncthreads();
        #pragma unroll
        for (int kc = 0; kc < 2; ++kc) {
            bf16x8 bf[2];
            #pragma unroll
            for (int fn = 0; fn < 2; ++fn) {
                int row = wn*32 + fn*16 + l16;
                int slot = (kc<<2) + lq;
                bf[fn] = *(const bf16x8*)(Bl + row*128 + ((slot ^ (row&7))<<4));
            }
            #pragma unroll
            for (int fm = 0; fm < 4; ++fm) {
                int row = wm*64 + fm*16 + l16;
                int slot = (kc<<2) + lq;
                bf16x8 af = *(const bf16x8*)(Al + row*128 + ((slot ^ (row&7))<<4));
                acc[fm][0] = __builtin_amdgcn_mfma_f32_16x16x32_bf16(af, bf[0], acc[fm][0], 0,0,0);
                acc[fm][1] = __builtin_amdgcn_mfma_f32_16x16x32_bf16(af, bf[1], acc[fm][1], 0,0,0);
            }
        }
        __syncthreads();
    }
    #pragma unroll
    for (int fm = 0; fm < 4; ++fm) {
        #pragma unroll
        for (int fn = 0; fn < 2; ++fn) {
            int n = bn + wn*32 + fn*16 + l16;
            float bv = bias[n];
            #pragma unroll
            for (int r = 0; r < 4; ++r) {
                long m = bm + wm*64 + fm*16 + lq*4 + r;
                float v = acc[fm][fn][r] + bv;
                if constexpr (MODE == MODE_F16) {
                    ((f16*)Cv)[m*ldc + n] = (f16)v;
                } else if constexpr (MODE == MODE_GELU_F16) {
                    ((f16*)Cv)[m*ldc + n] = (f16)gelu_tanh(v);
                } else {
                    float g = (float)gatebuf[m*ldg + n];
                    ((bf16*)Cv)[m*ldc + n] = __float2bfloat16(g * v);
                }
            }
        }
    }
}

// ---------------- sLSTM scan: 64 blocks (1 batch each), 512 threads ----------------
// Thread t owns outputs g0=t, g1=t+512. R rows: k<192 in VGPR (f16 pairs), k>=192 in LDS.
#define SCAN_SMEM (1024*128 + 512 + 4096)

__global__ __launch_bounds__(512, 2) void k_scan(
    const f16* __restrict__ xW, const f16* __restrict__ Rf,
    bf16* __restrict__ h_out)
{
    extern __shared__ char sm[];
    char* R_lds   = sm;                              // 1024 rows x 128B (swizzled)
    unsigned* h_u = (unsigned*)(sm + 1024*128);      // 128 u32 = 256 f16 (h pairs)
    float* pre    = (float*)(sm + 1024*128 + 512);   // 1024 f32
    const int tid = threadIdx.x;
    const int b = blockIdx.x;
    const int g0 = tid, g1 = tid + 512;

    uint4 R0q[24], R1q[24];
    const uint4* r0p = (const uint4*)(Rf + (long)g0*256);
    const uint4* r1p = (const uint4*)(Rf + (long)g1*256);
    #pragma unroll
    for (int j = 0; j < 24; ++j) { R0q[j] = r0p[j]; R1q[j] = r1p[j]; }
    #pragma unroll
    for (int s = 0; s < 8; ++s) {
        *(uint4*)(R_lds + g0*128 + ((s ^ (g0&7))<<4)) = r0p[24+s];
        *(uint4*)(R_lds + g1*128 + ((s ^ (g1&7))<<4)) = r1p[24+s];
    }
    if (tid < 128) h_u[tid] = 0u;
    float cst = 0.f, nst = 0.f, mst = 0.f;
    const f16* xrow = xW + (long)b * TT * G4;
    bf16* hrow = h_out + (long)b * TT * HDIM;
    __syncthreads();

    for (int t = 0; t < TT; ++t) {
        float xw0 = (float)xrow[g0];
        float xw1 = (float)xrow[g1];
        float a0a = 0.f, a0b = 0.f, a1a = 0.f, a1b = 0.f;
        const uint4* h4 = (const uint4*)h_u;
        #pragma unroll
        for (int jb = 0; jb < 24; ++jb) {
            uint4 hv = h4[jb];
            a0a = dot2f(R0q[jb].x, hv.x, a0a);
            a0b = dot2f(R0q[jb].y, hv.y, a0b);
            a0a = dot2f(R0q[jb].z, hv.z, a0a);
            a0b = dot2f(R0q[jb].w, hv.w, a0b);
            a1a = dot2f(R1q[jb].x, hv.x, a1a);
            a1b = dot2f(R1q[jb].y, hv.y, a1b);
            a1a = dot2f(R1q[jb].z, hv.z, a1a);
            a1b = dot2f(R1q[jb].w, hv.w, a1b);
        }
        #pragma unroll
        for (int s = 0; s < 8; ++s) {
            uint4 hv = h4[24+s];
            uint4 r0 = *(const uint4*)(R_lds + g0*128 + ((s ^ (g0&7))<<4));
            uint4 r1 = *(const uint4*)(R_lds + g1*128 + ((s ^ (g1&7))<<4));
            a0a = dot2f(r0.x, hv.x, a0a); a0b = dot2f(r0.y, hv.y, a0b);
            a0a = dot2f(r0.z, hv.z, a0a); a0b = dot2f(r0.w, hv.w, a0b);
            a1a = dot2f(r1.x, hv.x, a1a); a1b = dot2f(r1.y, hv.y, a1b);
            a1a = dot2f(r1.z, hv.z, a1a); a1b = dot2f(r1.w, hv.w, a1b);
        }
        pre[g0] = a0a + a0b + xw0;
        pre[g1] = a1a + a1b + xw1;
        __syncthreads();
        if (tid < HDIM) {
            float zp = pre[tid], li = pre[256+tid], lf = pre[512+tid], op = pre[768+tid];
            float e = __expf(-2.0f * fabsf(zp));
            float z = copysignf((1.0f - e) / (1.0f + e), zp);
            float o = 1.0f / (1.0f + __expf(-op));
            float mn = fmaxf(lf + mst, li);
            float ig = __expf(li - mn);
            float fg = __expf(lf + mst - mn);
            cst = fg*cst + ig*z;
            nst = fg*nst + ig;
            mst = mn;
            float h = o * (cst / nst);
            ((f16*)h_u)[tid] = (f16)h;
            hrow[tid] = __float2bfloat16(h);
        }
        __syncthreads();
        xrow += G4;
        hrow += HDIM;
    }
}

// ---------------- launch ----------------
extern "C" void kernel_launch(void* const* d_in, const int* in_sizes, int n_in,
                              void* d_out, int out_size, void* d_ws, size_t ws_size,
                              hipStream_t stream) {
    const float* x     = (const float*)d_in[0];
    const float* ln1w  = (const float*)d_in[1];
    const float* ln1b  = (const float*)d_in[2];
    const float* W     = (const float*)d_in[3];
    const float* R     = (const float*)d_in[4];
    const float* bg    = (const float*)d_in[5];
    const float* upW   = (const float*)d_in[6];
    const float* upb   = (const float*)d_in[7];
    const float* gateW = (const float*)d_in[8];
    const float* gateb = (const float*)d_in[9];
    const float* downW = (const float*)d_in[10];
    const float* downb = (const float*)d_in[11];
    const float* ln2w  = (const float*)d_in[12];
    const float* ln2b  = (const float*)d_in[13];

    char* ws = (char*)d_ws;
    size_t off = 0;
    auto alloc = [&](size_t bytes) { char* p = ws + off; off += (bytes + 255) & ~255ULL; return p; };
    f16*  mlp16   = (f16*)alloc((size_t)NTOK*HDIM*2);     // holds nx first, then mlp (disjoint lifetimes)
    char* regionB = alloc((size_t)NTOK*G4*2);             // xW, then gate_out+prod
    bf16* h       = (bf16*)alloc((size_t)NTOK*HDIM*2);
    bf16* Wb      = (bf16*)alloc(262144*2);
    f16*  Rf      = (f16*)alloc(262144*2);
    bf16* gWb     = (bf16*)alloc((size_t)MPAD*256*2);
    bf16* uWb     = (bf16*)alloc((size_t)MPAD*256*2);
    bf16* dWb     = (bf16*)alloc((size_t)256*MPAD*2);
    float* gbp    = (float*)alloc(MPAD*4);
    float* ubp    = (float*)alloc(MPAD*4);

    bf16* nx       = (bf16*)mlp16;                        // phase 1 use of that region
    f16*  xWb      = (f16*)regionB;                       // 131072 x 1024 f16
    f16*  gate_out = (f16*)regionB;                       // reuse after scan: 131072 x 384 f16
    bf16* prod     = (bf16*)(regionB + (size_t)NTOK*MPAD*2);

    hipFuncSetAttribute(reinterpret_cast<const void*>(&k_scan),
                        hipFuncAttributeMaxDynamicSharedMemorySize, SCAN_SMEM);

    k_prep_wr  <<<1024, 256, 0, stream>>>(W, R, Wb, Rf);
    k_prep_gu  <<<384, 256, 0, stream>>>(gateW, upW, gateb, upb, gWb, uWb, gbp, ubp);
    k_prep_down<<<384, 256, 0, stream>>>(downW, dWb);
    k_ln1      <<<NTOK/4, 256, 0, stream>>>(x, ln1w, ln1b, nx);
    // xW = nx @ W^T + b   (f16 out)
    k_gemm<MODE_F16><<<dim3(1024, 16), 256, 0, stream>>>(nx, Wb, bg, xWb, nullptr, 256, 256, 256, 1024, 0);
    // sequential sLSTM scan
    k_scan     <<<64, 512, SCAN_SMEM, stream>>>(xWb, Rf, h);
    // gate = gelu(h @ gateW^T + gate_b)  (f16)
    k_gemm<MODE_GELU_F16><<<dim3(1024, 6), 256, 0, stream>>>(h, gWb, gbp, gate_out, nullptr, 256, 256, 256, MPAD, 0);
    // prod = gate * (h @ upW^T + up_b)   (bf16, padded cols auto-zero)
    k_gemm<MODE_MUL_BF16><<<dim3(1024, 6), 256, 0, stream>>>(h, uWb, ubp, prod, gate_out, 256, 256, 256, MPAD, MPAD);
    // mlp = prod @ downW^T + down_b      (f16 out, K=384)
    k_gemm<MODE_F16><<<dim3(1024, 4), 256, 0, stream>>>(prod, dWb, downb, mlp16, nullptr, MPAD, MPAD, MPAD, HDIM, 0);
    // out = LN(mlp) + x
    k_ln2      <<<NTOK/4, 256, 0, stream>>>(mlp16, x, ln2w, ln2b, (float*)d_out);
}